// Round 3
// baseline (692.257 us; speedup 1.0000x reference)
//
#include <hip/hip_runtime.h>
#include <math.h>

#define NCLS 64
#define KS 5
#define DD 256
#define NQ 8192   // NCLS*128
#define KNB 10
#define QK 12     // per-chunk candidate list depth (need >=10 for exact containment)
#define NCH 8     // column chunks per row (1024 cols each)
#define CAND 96   // NCH * QK

typedef __attribute__((ext_vector_type(8))) short short8;   // 8 bf16 bit-patterns (4 VGPRs)
typedef __attribute__((ext_vector_type(4))) float f32x4;    // MFMA C/D frag

// row index in x (fp32 row units) of query g
__device__ __forceinline__ int qrow(int g) { return (g >> 7) * 133 + KS + (g & 127); }

__device__ __forceinline__ unsigned short bf16_rne(float f) {
    unsigned int u = __float_as_uint(f);
    u += 0x7fffu + ((u >> 16) & 1u);
    return (unsigned short)(u >> 16);
}

__device__ __forceinline__ float blk_reduce_sum(float v, float* red) {
    int t = threadIdx.x;
    red[t] = v; __syncthreads();
    for (int off = 128; off > 0; off >>= 1) {
        if (t < off) red[t] += red[t + off];
        __syncthreads();
    }
    float r = red[0];
    __syncthreads();
    return r;
}

__device__ __forceinline__ float blk_reduce_max(float v, float* red) {
    int t = threadIdx.x;
    red[t] = v; __syncthreads();
    for (int off = 128; off > 0; off >>= 1) {
        if (t < off) red[t] = fmaxf(red[t], red[t + off]);
        __syncthreads();
    }
    float r = red[0];
    __syncthreads();
    return r;
}

// ---------- K0: NORMALIZED bf16 cast of query rows + qInv ----------
__global__ __launch_bounds__(256) void split_kernel(const float* __restrict__ x,
                                                    unsigned short* __restrict__ xh,
                                                    float* __restrict__ qInv) {
    __shared__ float red[256];
    int g = blockIdx.x, t = threadIdx.x;
    float v = x[(long)qrow(g) * DD + t];
    float n2 = blk_reduce_sum(v * v, red);
    float inv = 1.f / sqrtf(n2);
    xh[g * DD + t] = bf16_rne(v * inv);
    if (t == 0) qInv[g] = inv;
}

// ---------- K1: proto, pn, self_sim ----------
__global__ __launch_bounds__(256) void proto_kernel(const float* __restrict__ x,
                                                    float* proto, float* pn, float* selfs) {
    __shared__ float red[256];
    int c = blockIdx.x, t = threadIdx.x;
    float s = 0.f;
    for (int j = 0; j < KS; j++) s += x[(long)(c * 133 + j) * DD + t];
    float p = s / 5.0f;
    proto[c * DD + t] = p;
    float n2 = blk_reduce_sum(p * p, red);
    float pv = p / sqrtf(n2);
    pn[c * DD + t] = pv;
    float ss = blk_reduce_sum(pv * pv, red);
    if (t == 0) selfs[c] = ss;
}

// ---------- K2: pre_sim argmax per query ----------
__global__ __launch_bounds__(256) void presim_kernel(const float* __restrict__ x,
                                                     const float* __restrict__ qInv,
                                                     const float* __restrict__ pn,
                                                     float* pre_max, int* pre_label) {
    __shared__ float qs[256];
    __shared__ float part[256];
    __shared__ float sims[64];
    int g = blockIdx.x, t = threadIdx.x;
    qs[t] = x[(long)qrow(g) * DD + t];
    __syncthreads();
    int c = t >> 2, tl = t & 3;
    float s = 0.f;
    for (int u = 0; u < 64; u++) s += qs[tl * 64 + u] * pn[c * DD + tl * 64 + u];
    part[t] = s; __syncthreads();
    if (tl == 0) sims[c] = part[t] + part[t + 1] + part[t + 2] + part[t + 3];
    __syncthreads();
    if (t == 0) {
        float best = sims[0]; int bi = 0;
        for (int c2 = 1; c2 < 64; c2++)
            if (sims[c2] > best) { best = sims[c2]; bi = c2; }
        pre_max[g] = best * qInv[g];
        pre_label[g] = bi;
    }
}

// ---------- K3: adapted prototypes — LDS-compacted member list ----------
__global__ __launch_bounds__(256) void adapt_proto_kernel(const float* __restrict__ x,
                                                          const float* __restrict__ proto,
                                                          const float* __restrict__ selfs,
                                                          const float* __restrict__ pre_max,
                                                          const int* __restrict__ pre_label,
                                                          float* apn) {
    __shared__ int lst[NQ];
    __shared__ float red[256];
    __shared__ int cnt_s;
    int c = blockIdx.x, t = threadIdx.x;
    if (t == 0) cnt_s = 0;
    __syncthreads();
    float lm = -INFINITY;
    for (int g = t; g < NQ; g += 256) {
        if (pre_label[g] == c) {
            int p = atomicAdd(&cnt_s, 1);
            lst[p] = g;
            lm = fmaxf(lm, pre_max[g]);
        }
    }
    float m = fmaxf(blk_reduce_max(lm, red), selfs[c]);   // barrier publishes lst/cnt_s
    int cnt = cnt_s;
    float ls = 0.f;
    for (int e = t; e < cnt; e += 256) ls += expf(pre_max[lst[e]] - m);
    float es = expf(selfs[c] - m);
    float Z = blk_reduce_sum(ls, red) + es;
    float acc = es * proto[c * DD + t];
    #pragma unroll 2
    for (int e = 0; e < cnt; e++) {
        int g = lst[e];
        acc += expf(pre_max[g] - m) * x[(long)qrow(g) * DD + t];
    }
    float ap = acc / Z;
    float n2 = blk_reduce_sum(ap * ap, red);
    apn[c * DD + t] = ap / sqrtf(n2);
}

// ---------- K4: bf16 MFMA coarse cosines, register scan + SW PIPELINE ----------
// R2 lesson: VGPR_Count=40 proved the compiler serialized load->wait->mfma per
// kc step (no room for in-flight fragments). Fix: __launch_bounds__(256,4)
// (VGPR cap 128 -- occupancy is grid-capped at 4 blocks/CU anyway, registers
// are free) + explicit 2-tile double buffer bufA/bufB: all 8 loads of tile
// t+1 issue BEFORE tile t's MFMA chain + scan, hiding ~200-300cyc L2 latency.
// Named arrays with compile-time indices only (runtime-indexed -> scratch).
#define COMPUTE_TILE(F, TILE)                                                      \
    {                                                                              \
        f32x4 acc = {0.f, 0.f, 0.f, 0.f};                                          \
        _Pragma("unroll")                                                          \
        for (int kc = 0; kc < 8; kc++)                                             \
            acc = __builtin_amdgcn_mfma_f32_16x16x32_bf16(F[kc], qh[kc], acc, 0, 0, 0); \
        _Pragma("unroll")                                                          \
        for (int r = 0; r < 4; ++r) {                                              \
            unsigned int u = __float_as_uint(acc[r]);                              \
            unsigned int key = u ^ (unsigned int)(((int)u >> 31) | 0x80000000);    \
            key = (key & 0xFFFFFC00u) | (unsigned int)((TILE) * 16 + 4 * qd + r);  \
            if (key > keys[QK - 1]) {                                              \
                unsigned int ck = key;                                             \
                _Pragma("unroll")                                                  \
                for (int p = 0; p < QK; ++p) {                                     \
                    bool sw = ck > keys[p];                                        \
                    unsigned int tmp = keys[p];                                    \
                    keys[p] = sw ? ck : keys[p];                                   \
                    ck = sw ? tmp : ck;                                            \
                }                                                                  \
            }                                                                      \
        }                                                                          \
    }

__global__ __launch_bounds__(256, 4) void simtopk_kernel(const unsigned short* __restrict__ xh,
                                                         int* __restrict__ topi4) {
    __shared__ unsigned int dump[4][13 * 64];   // per-wave 64 lanes x 12 keys, stride 13

    const int t = threadIdx.x;
    const int b = blockIdx.x;
    const int rb = b >> 3;          // 128 row-blocks of 64 rows
    const int ch = b & 7;           // column chunk
    const int row0 = rb * 64;
    const int col0 = ch * 1024;

    const int wv = t >> 6;
    const int lane = t & 63;
    const int qd = lane >> 4;
    const int nn = lane & 15;

    // Query fragments (MFMA B operand): lane holds Q[n=nn][k=kc*32+qd*8 ..+7]
    const int arow = (row0 + wv * 16 + nn) * DD;
    short8 qh[8];
    #pragma unroll
    for (int kc = 0; kc < 8; kc++)
        qh[kc] = *(const short8*)(xh + arow + kc * 32 + qd * 8);

    unsigned int keys[QK];
    #pragma unroll
    for (int s = 0; s < QK; s++) keys[s] = 0u;   // below any real score's key

    // per-lane candidate-fragment base: cand row (col0 + tile*16 + nn), byte
    // offset qd*8 shorts. Tile stride = 16 rows * DD = 4096 shorts.
    const unsigned short* base = xh + (long)(col0 + nn) * DD + qd * 8;

    short8 bufA[8], bufB[8];
    #pragma unroll
    for (int kc = 0; kc < 8; kc++) bufA[kc] = *(const short8*)(base + kc * 32);

    #pragma unroll 1
    for (int t2 = 0; t2 < 32; ++t2) {
        const unsigned short* nb = base + 4096;            // tile 2*t2+1
        #pragma unroll
        for (int kc = 0; kc < 8; kc++) bufB[kc] = *(const short8*)(nb + kc * 32);
        COMPUTE_TILE(bufA, 2 * t2)
        base += 8192;                                      // tile 2*t2+2
        if (t2 < 31) {
            #pragma unroll
            for (int kc = 0; kc < 8; kc++) bufA[kc] = *(const short8*)(base + kc * 32);
        }
        COMPUTE_TILE(bufB, 2 * t2 + 1)
    }

    // dump (wave-private, in-order DS: no barrier) + per-query 4-list merge.
    // Query nn's lists live at lanes nn, nn+16, nn+32, nn+48.
    unsigned int* dw = &dump[wv][0];
    #pragma unroll
    for (int s = 0; s < QK; s++) dw[lane * 13 + s] = keys[s];
    if (lane < 16) {
        const int g = row0 + wv * 16 + lane;
        const int b0 = (lane +  0) * 13;
        const int b1 = (lane + 16) * 13;
        const int b2 = (lane + 32) * 13;
        const int b3 = (lane + 48) * 13;
        int p0 = 0, p1 = 0, p2 = 0, p3 = 0;
        for (int s = 0; s < QK; s++) {
            unsigned int v0 = (p0 < QK) ? dw[b0 + p0] : 0u;
            unsigned int v1 = (p1 < QK) ? dw[b1 + p1] : 0u;
            unsigned int v2 = (p2 < QK) ? dw[b2 + p2] : 0u;
            unsigned int v3 = (p3 < QK) ? dw[b3 + p3] : 0u;
            unsigned int bv = v0; int bw = 0;
            if (v1 > bv) { bv = v1; bw = 1; }
            if (v2 > bv) { bv = v2; bw = 2; }
            if (v3 > bv) { bv = v3; bw = 3; }
            topi4[g * CAND + ch * QK + s] = col0 + (int)(bv & 1023u);
            if (bw == 0) p0++; else if (bw == 1) p1++; else if (bw == 2) p2++; else p3++;
        }
    }
}

// ---------- K5: exact fp32 rescoring, fully-coalesced (block = 1 query) ----------
// 64 lanes per candidate: one float4 wave-load = the whole 1 KB row. Next
// pass's candidate index prefetched one iteration early (breaks the
// topi4->row dependent ~400cyc chain).
__global__ __launch_bounds__(256) void rescore_kernel(const float* __restrict__ x,
                                                      const float* __restrict__ qInv,
                                                      const int* __restrict__ topi4,
                                                      float* __restrict__ topv,
                                                      int* __restrict__ topi) {
    __shared__ float sc[CAND];
    __shared__ int   si[CAND];
    const int g = blockIdx.x;
    const int t = threadIdx.x;
    const int lane = t & 63;
    const int w = t >> 6;            // candidate sub-slot 0..3
    const float4 a4 = *(const float4*)(x + (long)qrow(g) * DD + lane * 4);
    const float qg = qInv[g];
    int jn = topi4[g * CAND + w];
    #pragma unroll 4
    for (int pass = 0; pass < CAND / 4; ++pass) {
        const int c = pass * 4 + w;
        int j = jn;
        if (pass < CAND / 4 - 1) jn = topi4[g * CAND + c + 4];
        if ((unsigned)j >= NQ) j = 0;
        const float4 b4 = *(const float4*)(x + (long)qrow(j) * DD + lane * 4);
        float p = a4.x * b4.x + a4.y * b4.y + a4.z * b4.z + a4.w * b4.w;
        #pragma unroll
        for (int off = 32; off > 0; off >>= 1) p += __shfl_xor(p, off);
        if (lane == 0) { sc[c] = p * qInv[j] * qg; si[c] = j; }
    }
    __syncthreads();
    if (t == 0) {
        float Lv[KNB]; int Li[KNB];
        for (int s = 0; s < KNB; s++) { Lv[s] = -INFINITY; Li[s] = 0x7fffffff; }
        #pragma unroll 4
        for (int q = 0; q < CAND; q++) {
            float v = sc[q]; int idx = si[q];
            if (v > Lv[KNB - 1] || (v == Lv[KNB - 1] && idx < Li[KNB - 1])) {
                int p = KNB - 1;
                while (p > 0 && (Lv[p - 1] < v || (Lv[p - 1] == v && Li[p - 1] > idx))) {
                    Lv[p] = Lv[p - 1]; Li[p] = Li[p - 1]; p--;
                }
                Lv[p] = v; Li[p] = idx;
            }
        }
        for (int s = 0; s < KNB; s++) {
            topv[g * KNB + s] = Lv[s];
            topi[g * KNB + s] = Li[s];
        }
    }
}

// ---------- K6: mutual-kNN softmax, adapted query, final cos sims ----------
__global__ __launch_bounds__(256) void final_kernel(const float* __restrict__ x,
                                                    const float* __restrict__ apn,
                                                    const float* __restrict__ topv,
                                                    const int* __restrict__ topi,
                                                    const float* __restrict__ tao_raw,
                                                    float* out) {
    __shared__ float tv[KNB]; __shared__ int ti[KNB]; __shared__ float w[KNB];
    __shared__ float aq[256]; __shared__ float red[256];
    int i = blockIdx.x, t = threadIdx.x;
    if (t < KNB) {
        tv[t] = topv[i * KNB + t];
        int j = topi[i * KNB + t];
        ti[t] = ((unsigned)j < NQ) ? j : 0;
    }
    __syncthreads();
    if (t < KNB) {
        int j = ti[t];
        bool mut = false;
        for (int s = 0; s < KNB; s++) mut = mut || (topi[j * KNB + s] == i);
        w[t] = mut ? tv[t] : -INFINITY;
    }
    __syncthreads();
    if (t == 0) {
        float m = -INFINITY;
        for (int s = 0; s < KNB; s++) m = fmaxf(m, w[s]);
        float e[KNB]; float Z = 0.f;
        for (int s = 0; s < KNB; s++) { e[s] = expf(w[s] - m); Z += e[s]; }
        for (int s = 0; s < KNB; s++) w[s] = e[s] / Z;
    }
    __syncthreads();
    float a = 0.f;
    for (int s = 0; s < KNB; s++) {
        float ws = w[s];
        if (ws != 0.f) a += ws * x[(long)qrow(ti[s]) * DD + t];
    }
    aq[t] = a;
    float n2 = blk_reduce_sum(a * a, red);
    float inv = 1.f / sqrtf(n2);
    int c = t >> 2, tl = t & 3;
    float sdot = 0.f;
    for (int u = 0; u < 64; u++) sdot += aq[tl * 64 + u] * apn[c * DD + tl * 64 + u];
    red[t] = sdot; __syncthreads();
    if (tl == 0) {
        float sv = red[t] + red[t + 1] + red[t + 2] + red[t + 3];
        out[i * NCLS + c] = tao_raw[0] * sv * inv;
    }
}

extern "C" void kernel_launch(void* const* d_in, const int* in_sizes, int n_in,
                              void* d_out, int out_size, void* d_ws, size_t ws_size,
                              hipStream_t stream) {
    (void)in_sizes; (void)n_in; (void)out_size;
    const float* x   = (const float*)d_in[0];
    const float* tao = (const float*)d_in[1];
    float* out = (float*)d_out;

    char* ws = (char*)d_ws;
    size_t off = 0;
    auto carve = [&](size_t bytes) {
        void* p = ws + off;
        off = (off + bytes + 255) & ~(size_t)255;
        return p;
    };
    float*          proto   = (float*)carve(NCLS * DD * 4);
    float*          pn      = (float*)carve(NCLS * DD * 4);
    float*          selfs   = (float*)carve(NCLS * 4);
    float*          qInv    = (float*)carve(NQ * 4);
    float*          pre_max = (float*)carve(NQ * 4);
    int*            pre_lab = (int*)carve(NQ * 4);
    float*          apn     = (float*)carve(NCLS * DD * 4);
    unsigned short* xh      = (unsigned short*)carve((size_t)NQ * DD * 2);
    int*            topi4   = (int*)carve((size_t)NQ * CAND * 4);
    float*          topv    = (float*)carve((size_t)NQ * KNB * 4);
    int*            topi    = (int*)carve((size_t)NQ * KNB * 4);
    if (off > ws_size) return;

    split_kernel<<<NQ, 256, 0, stream>>>(x, xh, qInv);
    proto_kernel<<<NCLS, 256, 0, stream>>>(x, proto, pn, selfs);
    presim_kernel<<<NQ, 256, 0, stream>>>(x, qInv, pn, pre_max, pre_lab);
    adapt_proto_kernel<<<NCLS, 256, 0, stream>>>(x, proto, selfs, pre_max, pre_lab, apn);
    simtopk_kernel<<<NQ / 64 * NCH, 256, 0, stream>>>(xh, topi4);
    rescore_kernel<<<NQ, 256, 0, stream>>>(x, qInv, topi4, topv, topi);
    final_kernel<<<NQ, 256, 0, stream>>>(x, apn, topv, topi, tao, out);
}

// Round 4
// 486.913 us; speedup vs baseline: 1.4217x; 1.4217x over previous
//
#include <hip/hip_runtime.h>
#include <math.h>

#define NCLS 64
#define KS 5
#define DD 256
#define NQ 8192   // NCLS*128
#define KNB 10
#define QK 12     // per-chunk candidate list depth (need >=10 for exact containment)
#define NCH 8     // column chunks per row (1024 cols each)
#define CAND 96   // NCH * QK

typedef __attribute__((ext_vector_type(8))) short short8;   // 8 bf16 bit-patterns (4 VGPRs)
typedef __attribute__((ext_vector_type(4))) float f32x4;    // MFMA C/D frag

// row index in x (fp32 row units) of query g
__device__ __forceinline__ int qrow(int g) { return (g >> 7) * 133 + KS + (g & 127); }

__device__ __forceinline__ unsigned short bf16_rne(float f) {
    unsigned int u = __float_as_uint(f);
    u += 0x7fffu + ((u >> 16) & 1u);
    return (unsigned short)(u >> 16);
}

__device__ __forceinline__ float blk_reduce_sum(float v, float* red) {
    int t = threadIdx.x;
    red[t] = v; __syncthreads();
    for (int off = 128; off > 0; off >>= 1) {
        if (t < off) red[t] += red[t + off];
        __syncthreads();
    }
    float r = red[0];
    __syncthreads();
    return r;
}

__device__ __forceinline__ float blk_reduce_max(float v, float* red) {
    int t = threadIdx.x;
    red[t] = v; __syncthreads();
    for (int off = 128; off > 0; off >>= 1) {
        if (t < off) red[t] = fmaxf(red[t], red[t + off]);
        __syncthreads();
    }
    float r = red[0];
    __syncthreads();
    return r;
}

// ---------- K0: NORMALIZED bf16 cast of query rows + qInv ----------
__global__ __launch_bounds__(256) void split_kernel(const float* __restrict__ x,
                                                    unsigned short* __restrict__ xh,
                                                    float* __restrict__ qInv) {
    __shared__ float red[256];
    int g = blockIdx.x, t = threadIdx.x;
    float v = x[(long)qrow(g) * DD + t];
    float n2 = blk_reduce_sum(v * v, red);
    float inv = 1.f / sqrtf(n2);
    xh[g * DD + t] = bf16_rne(v * inv);
    if (t == 0) qInv[g] = inv;
}

// ---------- K1: proto, pn, self_sim ----------
__global__ __launch_bounds__(256) void proto_kernel(const float* __restrict__ x,
                                                    float* proto, float* pn, float* selfs) {
    __shared__ float red[256];
    int c = blockIdx.x, t = threadIdx.x;
    float s = 0.f;
    for (int j = 0; j < KS; j++) s += x[(long)(c * 133 + j) * DD + t];
    float p = s / 5.0f;
    proto[c * DD + t] = p;
    float n2 = blk_reduce_sum(p * p, red);
    float pv = p / sqrtf(n2);
    pn[c * DD + t] = pv;
    float ss = blk_reduce_sum(pv * pv, red);
    if (t == 0) selfs[c] = ss;
}

// ---------- K2: pre_sim argmax per query ----------
__global__ __launch_bounds__(256) void presim_kernel(const float* __restrict__ x,
                                                     const float* __restrict__ qInv,
                                                     const float* __restrict__ pn,
                                                     float* pre_max, int* pre_label) {
    __shared__ float qs[256];
    __shared__ float part[256];
    __shared__ float sims[64];
    int g = blockIdx.x, t = threadIdx.x;
    qs[t] = x[(long)qrow(g) * DD + t];
    __syncthreads();
    int c = t >> 2, tl = t & 3;
    float s = 0.f;
    for (int u = 0; u < 64; u++) s += qs[tl * 64 + u] * pn[c * DD + tl * 64 + u];
    part[t] = s; __syncthreads();
    if (tl == 0) sims[c] = part[t] + part[t + 1] + part[t + 2] + part[t + 3];
    __syncthreads();
    if (t == 0) {
        float best = sims[0]; int bi = 0;
        for (int c2 = 1; c2 < 64; c2++)
            if (sims[c2] > best) { best = sims[c2]; bi = c2; }
        pre_max[g] = best * qInv[g];
        pre_label[g] = bi;
    }
}

// ---------- K3: adapted prototypes — LDS-compacted member list ----------
__global__ __launch_bounds__(256) void adapt_proto_kernel(const float* __restrict__ x,
                                                          const float* __restrict__ proto,
                                                          const float* __restrict__ selfs,
                                                          const float* __restrict__ pre_max,
                                                          const int* __restrict__ pre_label,
                                                          float* apn) {
    __shared__ int lst[NQ];
    __shared__ float red[256];
    __shared__ int cnt_s;
    int c = blockIdx.x, t = threadIdx.x;
    if (t == 0) cnt_s = 0;
    __syncthreads();
    float lm = -INFINITY;
    for (int g = t; g < NQ; g += 256) {
        if (pre_label[g] == c) {
            int p = atomicAdd(&cnt_s, 1);
            lst[p] = g;
            lm = fmaxf(lm, pre_max[g]);
        }
    }
    float m = fmaxf(blk_reduce_max(lm, red), selfs[c]);   // barrier publishes lst/cnt_s
    int cnt = cnt_s;
    float ls = 0.f;
    for (int e = t; e < cnt; e += 256) ls += expf(pre_max[lst[e]] - m);
    float es = expf(selfs[c] - m);
    float Z = blk_reduce_sum(ls, red) + es;
    float acc = es * proto[c * DD + t];
    #pragma unroll 2
    for (int e = 0; e < cnt; e++) {
        int g = lst[e];
        acc += expf(pre_max[g] - m) * x[(long)qrow(g) * DD + t];
    }
    float ap = acc / Z;
    float n2 = blk_reduce_sum(ap * ap, red);
    apn[c * DD + t] = ap / sqrtf(n2);
}

// ---------- K4: bf16 MFMA coarse cosines, LDS-STAGED candidate tiles ----------
// R3 lesson: 64-VGPR reg double-buffer spilled to scratch (WRITE_SIZE 4->88MB).
// Structural fix: within a block all 4 waves scan the SAME candidate columns,
// so stage each 8KB tile (16 cand rows x 256 bf16, contiguous in xh) in LDS
// ONCE per block (reg-staged T14 split: gload early, ds_write after barrier;
// only 8 staging VGPRs). All 4 waves ds_read fragments from LDS.
// XOR swizzle on 16B units (u = r*32 + (c ^ (r&7))): row stride 512B is
// 0 mod banks, so unswizzled reads put 16 lanes/bank-cluster (2x LDS cost);
// swizzled, reads AND writes are balanced 8/cluster = the 8-clk BW floor.
#define COMPUTE_TILE_L(LBUF, TILE)                                                 \
    {                                                                              \
        f32x4 acc = {0.f, 0.f, 0.f, 0.f};                                          \
        _Pragma("unroll")                                                          \
        for (int kc = 0; kc < 8; kc++) {                                           \
            short8 cf = *(const short8*)((LBUF) + ((nn << 8) + (((kc * 4 + qd) ^ xm) << 3))); \
            acc = __builtin_amdgcn_mfma_f32_16x16x32_bf16(cf, qh[kc], acc, 0, 0, 0); \
        }                                                                          \
        _Pragma("unroll")                                                          \
        for (int r = 0; r < 4; ++r) {                                              \
            unsigned int u = __float_as_uint(acc[r]);                              \
            unsigned int key = u ^ (unsigned int)(((int)u >> 31) | 0x80000000);    \
            key = (key & 0xFFFFFC00u) | (unsigned int)((TILE) * 16 + 4 * qd + r);  \
            if (key > keys[QK - 1]) {                                              \
                unsigned int ck = key;                                             \
                _Pragma("unroll")                                                  \
                for (int p = 0; p < QK; ++p) {                                     \
                    bool sw = ck > keys[p];                                        \
                    unsigned int tmp = keys[p];                                    \
                    keys[p] = sw ? ck : keys[p];                                   \
                    ck = sw ? tmp : ck;                                            \
                }                                                                  \
            }                                                                      \
        }                                                                          \
    }

// load tile TL's two 16B units (G0=t, G1=256+t) into regs
#define GLOAD(RA, RB, TL)                                                          \
    {                                                                              \
        const unsigned short* tb = xh + ((size_t)(col0 + (TL) * 16) << 8);         \
        RA = *(const uint4*)(tb + (G0 << 3));                                      \
        RB = *(const uint4*)(tb + (G1 << 3));                                      \
    }

// swizzled LDS write: unit u0/u1 precomputed from G0/G1
#define DSWRITE(LBUF, RA, RB)                                                      \
    {                                                                              \
        *(uint4*)((LBUF) + (u0 << 3)) = RA;                                        \
        *(uint4*)((LBUF) + (u1 << 3)) = RB;                                        \
    }

__global__ __launch_bounds__(256, 4) void simtopk_kernel(const unsigned short* __restrict__ xh,
                                                         int* __restrict__ topi4) {
    __shared__ uint4 smem4[1024];   // 16 KB: 2x8KB tile double-buffer; aliased as dump
    unsigned short* T0 = (unsigned short*)smem4;
    unsigned short* T1 = (unsigned short*)smem4 + 4096;

    const int t = threadIdx.x;
    const int b = blockIdx.x;
    const int rb = b >> 3;          // 128 row-blocks of 64 rows
    const int ch = b & 7;           // column chunk
    const int row0 = rb * 64;
    const int col0 = ch * 1024;

    const int wv = t >> 6;
    const int lane = t & 63;
    const int qd = lane >> 4;
    const int nn = lane & 15;
    const int xm = nn & 7;

    // staging geometry: tile = 512 x 16B units; thread handles G0=t, G1=256+t
    const int G0 = t;
    const int G1 = 256 + t;
    const int r0r = G0 >> 5, c0u = G0 & 31;
    const int u0 = r0r * 32 + (c0u ^ (r0r & 7));
    const int r1r = G1 >> 5, c1u = G1 & 31;
    const int u1 = r1r * 32 + (c1u ^ (r1r & 7));

    // Query fragments (MFMA B operand): lane holds Q[n=nn][k=kc*32+qd*8 ..+7]
    const int arow = (row0 + wv * 16 + nn) * DD;
    short8 qh[8];
    #pragma unroll
    for (int kc = 0; kc < 8; kc++)
        qh[kc] = *(const short8*)(xh + arow + kc * 32 + qd * 8);

    unsigned int keys[QK];
    #pragma unroll
    for (int s = 0; s < QK; s++) keys[s] = 0u;   // below any real score's key

    uint4 RA, RB;
    GLOAD(RA, RB, 0)
    DSWRITE(T0, RA, RB)
    __syncthreads();                         // T0 ready

    #pragma unroll 1
    for (int t2 = 0; t2 < 32; ++t2) {
        GLOAD(RA, RB, 2 * t2 + 1)            // issue early (hides under compute)
        COMPUTE_TILE_L(T0, 2 * t2)
        __syncthreads();                     // all waves done reading T1 (prev iter)
        DSWRITE(T1, RA, RB)
        if (t2 < 31) GLOAD(RA, RB, 2 * t2 + 2)
        __syncthreads();                     // T1 ready
        COMPUTE_TILE_L(T1, 2 * t2 + 1)
        __syncthreads();                     // all waves done reading T0
        if (t2 < 31) { DSWRITE(T0, RA, RB) }
        __syncthreads();                     // T0 ready
    }

    // dump (aliases tile buffers; all tile reads are behind the final barrier).
    // Wave-private, in-order DS: no barrier needed. Query nn's lists live at
    // lanes nn, nn+16, nn+32, nn+48.
    unsigned int* dw = (unsigned int*)smem4 + wv * (13 * 64);
    #pragma unroll
    for (int s = 0; s < QK; s++) dw[lane * 13 + s] = keys[s];
    if (lane < 16) {
        const int g = row0 + wv * 16 + lane;
        const int b0 = (lane +  0) * 13;
        const int b1 = (lane + 16) * 13;
        const int b2 = (lane + 32) * 13;
        const int b3 = (lane + 48) * 13;
        int p0 = 0, p1 = 0, p2 = 0, p3 = 0;
        for (int s = 0; s < QK; s++) {
            unsigned int v0 = (p0 < QK) ? dw[b0 + p0] : 0u;
            unsigned int v1 = (p1 < QK) ? dw[b1 + p1] : 0u;
            unsigned int v2 = (p2 < QK) ? dw[b2 + p2] : 0u;
            unsigned int v3 = (p3 < QK) ? dw[b3 + p3] : 0u;
            unsigned int bv = v0; int bw = 0;
            if (v1 > bv) { bv = v1; bw = 1; }
            if (v2 > bv) { bv = v2; bw = 2; }
            if (v3 > bv) { bv = v3; bw = 3; }
            topi4[g * CAND + ch * QK + s] = col0 + (int)(bv & 1023u);
            if (bw == 0) p0++; else if (bw == 1) p1++; else if (bw == 2) p2++; else p3++;
        }
    }
}

// ---------- K5: exact fp32 rescoring, fully-coalesced (block = 1 query) ----------
__global__ __launch_bounds__(256) void rescore_kernel(const float* __restrict__ x,
                                                      const float* __restrict__ qInv,
                                                      const int* __restrict__ topi4,
                                                      float* __restrict__ topv,
                                                      int* __restrict__ topi) {
    __shared__ float sc[CAND];
    __shared__ int   si[CAND];
    const int g = blockIdx.x;
    const int t = threadIdx.x;
    const int lane = t & 63;
    const int w = t >> 6;            // candidate sub-slot 0..3
    const float4 a4 = *(const float4*)(x + (long)qrow(g) * DD + lane * 4);
    const float qg = qInv[g];
    int jn = topi4[g * CAND + w];
    #pragma unroll 4
    for (int pass = 0; pass < CAND / 4; ++pass) {
        const int c = pass * 4 + w;
        int j = jn;
        if (pass < CAND / 4 - 1) jn = topi4[g * CAND + c + 4];
        if ((unsigned)j >= NQ) j = 0;
        const float4 b4 = *(const float4*)(x + (long)qrow(j) * DD + lane * 4);
        float p = a4.x * b4.x + a4.y * b4.y + a4.z * b4.z + a4.w * b4.w;
        #pragma unroll
        for (int off = 32; off > 0; off >>= 1) p += __shfl_xor(p, off);
        if (lane == 0) { sc[c] = p * qInv[j] * qg; si[c] = j; }
    }
    __syncthreads();
    if (t == 0) {
        float Lv[KNB]; int Li[KNB];
        for (int s = 0; s < KNB; s++) { Lv[s] = -INFINITY; Li[s] = 0x7fffffff; }
        #pragma unroll 4
        for (int q = 0; q < CAND; q++) {
            float v = sc[q]; int idx = si[q];
            if (v > Lv[KNB - 1] || (v == Lv[KNB - 1] && idx < Li[KNB - 1])) {
                int p = KNB - 1;
                while (p > 0 && (Lv[p - 1] < v || (Lv[p - 1] == v && Li[p - 1] > idx))) {
                    Lv[p] = Lv[p - 1]; Li[p] = Li[p - 1]; p--;
                }
                Lv[p] = v; Li[p] = idx;
            }
        }
        for (int s = 0; s < KNB; s++) {
            topv[g * KNB + s] = Lv[s];
            topi[g * KNB + s] = Li[s];
        }
    }
}

// ---------- K6: mutual-kNN softmax, adapted query, final cos sims ----------
__global__ __launch_bounds__(256) void final_kernel(const float* __restrict__ x,
                                                    const float* __restrict__ apn,
                                                    const float* __restrict__ topv,
                                                    const int* __restrict__ topi,
                                                    const float* __restrict__ tao_raw,
                                                    float* out) {
    __shared__ float tv[KNB]; __shared__ int ti[KNB]; __shared__ float w[KNB];
    __shared__ float aq[256]; __shared__ float red[256];
    int i = blockIdx.x, t = threadIdx.x;
    if (t < KNB) {
        tv[t] = topv[i * KNB + t];
        int j = topi[i * KNB + t];
        ti[t] = ((unsigned)j < NQ) ? j : 0;
    }
    __syncthreads();
    if (t < KNB) {
        int j = ti[t];
        bool mut = false;
        for (int s = 0; s < KNB; s++) mut = mut || (topi[j * KNB + s] == i);
        w[t] = mut ? tv[t] : -INFINITY;
    }
    __syncthreads();
    if (t == 0) {
        float m = -INFINITY;
        for (int s = 0; s < KNB; s++) m = fmaxf(m, w[s]);
        float e[KNB]; float Z = 0.f;
        for (int s = 0; s < KNB; s++) { e[s] = expf(w[s] - m); Z += e[s]; }
        for (int s = 0; s < KNB; s++) w[s] = e[s] / Z;
    }
    __syncthreads();
    float a = 0.f;
    for (int s = 0; s < KNB; s++) {
        float ws = w[s];
        if (ws != 0.f) a += ws * x[(long)qrow(ti[s]) * DD + t];
    }
    aq[t] = a;
    float n2 = blk_reduce_sum(a * a, red);
    float inv = 1.f / sqrtf(n2);
    int c = t >> 2, tl = t & 3;
    float sdot = 0.f;
    for (int u = 0; u < 64; u++) sdot += aq[tl * 64 + u] * apn[c * DD + tl * 64 + u];
    red[t] = sdot; __syncthreads();
    if (tl == 0) {
        float sv = red[t] + red[t + 1] + red[t + 2] + red[t + 3];
        out[i * NCLS + c] = tao_raw[0] * sv * inv;
    }
}

extern "C" void kernel_launch(void* const* d_in, const int* in_sizes, int n_in,
                              void* d_out, int out_size, void* d_ws, size_t ws_size,
                              hipStream_t stream) {
    (void)in_sizes; (void)n_in; (void)out_size;
    const float* x   = (const float*)d_in[0];
    const float* tao = (const float*)d_in[1];
    float* out = (float*)d_out;

    char* ws = (char*)d_ws;
    size_t off = 0;
    auto carve = [&](size_t bytes) {
        void* p = ws + off;
        off = (off + bytes + 255) & ~(size_t)255;
        return p;
    };
    float*          proto   = (float*)carve(NCLS * DD * 4);
    float*          pn      = (float*)carve(NCLS * DD * 4);
    float*          selfs   = (float*)carve(NCLS * 4);
    float*          qInv    = (float*)carve(NQ * 4);
    float*          pre_max = (float*)carve(NQ * 4);
    int*            pre_lab = (int*)carve(NQ * 4);
    float*          apn     = (float*)carve(NCLS * DD * 4);
    unsigned short* xh      = (unsigned short*)carve((size_t)NQ * DD * 2);
    int*            topi4   = (int*)carve((size_t)NQ * CAND * 4);
    float*          topv    = (float*)carve((size_t)NQ * KNB * 4);
    int*            topi    = (int*)carve((size_t)NQ * KNB * 4);
    if (off > ws_size) return;

    split_kernel<<<NQ, 256, 0, stream>>>(x, xh, qInv);
    proto_kernel<<<NCLS, 256, 0, stream>>>(x, proto, pn, selfs);
    presim_kernel<<<NQ, 256, 0, stream>>>(x, qInv, pn, pre_max, pre_lab);
    adapt_proto_kernel<<<NCLS, 256, 0, stream>>>(x, proto, selfs, pre_max, pre_lab, apn);
    simtopk_kernel<<<NQ / 64 * NCH, 256, 0, stream>>>(xh, topi4);
    rescore_kernel<<<NQ, 256, 0, stream>>>(x, qInv, topi4, topv, topi);
    final_kernel<<<NQ, 256, 0, stream>>>(x, apn, topv, topi, tao, out);
}

// Round 5
// 448.777 us; speedup vs baseline: 1.5425x; 1.0850x over previous
//
#include <hip/hip_runtime.h>
#include <math.h>

#define NCLS 64
#define KS 5
#define DD 256
#define NQ 8192   // NCLS*128
#define KNB 10
#define QK 12     // per-chunk candidate list depth (need >=10 for exact containment)
#define NCH 8     // column chunks per row (1024 cols each)
#define CAND 96   // NCH * QK

typedef __attribute__((ext_vector_type(8))) short short8;   // 8 bf16 bit-patterns (4 VGPRs)
typedef __attribute__((ext_vector_type(4))) float f32x4;    // MFMA C/D frag

// row index in x (fp32 row units) of query g
__device__ __forceinline__ int qrow(int g) { return (g >> 7) * 133 + KS + (g & 127); }

__device__ __forceinline__ unsigned short bf16_rne(float f) {
    unsigned int u = __float_as_uint(f);
    u += 0x7fffu + ((u >> 16) & 1u);
    return (unsigned short)(u >> 16);
}

__device__ __forceinline__ float blk_reduce_sum(float v, float* red) {
    int t = threadIdx.x;
    red[t] = v; __syncthreads();
    for (int off = 128; off > 0; off >>= 1) {
        if (t < off) red[t] += red[t + off];
        __syncthreads();
    }
    float r = red[0];
    __syncthreads();
    return r;
}

__device__ __forceinline__ float blk_reduce_max(float v, float* red) {
    int t = threadIdx.x;
    red[t] = v; __syncthreads();
    for (int off = 128; off > 0; off >>= 1) {
        if (t < off) red[t] = fmaxf(red[t], red[t + off]);
        __syncthreads();
    }
    float r = red[0];
    __syncthreads();
    return r;
}

// ---------- K0: NORMALIZED bf16 cast of query rows + qInv ----------
__global__ __launch_bounds__(256) void split_kernel(const float* __restrict__ x,
                                                    unsigned short* __restrict__ xh,
                                                    float* __restrict__ qInv) {
    __shared__ float red[256];
    int g = blockIdx.x, t = threadIdx.x;
    float v = x[(long)qrow(g) * DD + t];
    float n2 = blk_reduce_sum(v * v, red);
    float inv = 1.f / sqrtf(n2);
    xh[g * DD + t] = bf16_rne(v * inv);
    if (t == 0) qInv[g] = inv;
}

// ---------- K1: proto, pn, self_sim ----------
__global__ __launch_bounds__(256) void proto_kernel(const float* __restrict__ x,
                                                    float* proto, float* pn, float* selfs) {
    __shared__ float red[256];
    int c = blockIdx.x, t = threadIdx.x;
    float s = 0.f;
    for (int j = 0; j < KS; j++) s += x[(long)(c * 133 + j) * DD + t];
    float p = s / 5.0f;
    proto[c * DD + t] = p;
    float n2 = blk_reduce_sum(p * p, red);
    float pv = p / sqrtf(n2);
    pn[c * DD + t] = pv;
    float ss = blk_reduce_sum(pv * pv, red);
    if (t == 0) selfs[c] = ss;
}

// ---------- K2: pre_sim argmax per query ----------
__global__ __launch_bounds__(256) void presim_kernel(const float* __restrict__ x,
                                                     const float* __restrict__ qInv,
                                                     const float* __restrict__ pn,
                                                     float* pre_max, int* pre_label) {
    __shared__ float qs[256];
    __shared__ float part[256];
    __shared__ float sims[64];
    int g = blockIdx.x, t = threadIdx.x;
    qs[t] = x[(long)qrow(g) * DD + t];
    __syncthreads();
    int c = t >> 2, tl = t & 3;
    float s = 0.f;
    for (int u = 0; u < 64; u++) s += qs[tl * 64 + u] * pn[c * DD + tl * 64 + u];
    part[t] = s; __syncthreads();
    if (tl == 0) sims[c] = part[t] + part[t + 1] + part[t + 2] + part[t + 3];
    __syncthreads();
    if (t == 0) {
        float best = sims[0]; int bi = 0;
        for (int c2 = 1; c2 < 64; c2++)
            if (sims[c2] > best) { best = sims[c2]; bi = c2; }
        pre_max[g] = best * qInv[g];
        pre_label[g] = bi;
    }
}

// ---------- K3: adapted prototypes — LDS-compacted member list ----------
// R4: member-accumulation loop gets 4 independent accumulators (was a serial
// dependent-gather chain, ~400cyc/member at 64 blocks).
__global__ __launch_bounds__(256) void adapt_proto_kernel(const float* __restrict__ x,
                                                          const float* __restrict__ proto,
                                                          const float* __restrict__ selfs,
                                                          const float* __restrict__ pre_max,
                                                          const int* __restrict__ pre_label,
                                                          float* apn) {
    __shared__ int lst[NQ];
    __shared__ float red[256];
    __shared__ int cnt_s;
    int c = blockIdx.x, t = threadIdx.x;
    if (t == 0) cnt_s = 0;
    __syncthreads();
    float lm = -INFINITY;
    for (int g = t; g < NQ; g += 256) {
        if (pre_label[g] == c) {
            int p = atomicAdd(&cnt_s, 1);
            lst[p] = g;
            lm = fmaxf(lm, pre_max[g]);
        }
    }
    float m = fmaxf(blk_reduce_max(lm, red), selfs[c]);   // barrier publishes lst/cnt_s
    int cnt = cnt_s;
    float ls = 0.f;
    for (int e = t; e < cnt; e += 256) ls += expf(pre_max[lst[e]] - m);
    float es = expf(selfs[c] - m);
    float Z = blk_reduce_sum(ls, red) + es;
    float a0 = es * proto[c * DD + t], a1 = 0.f, a2 = 0.f, a3 = 0.f;
    int e = 0;
    for (; e + 3 < cnt; e += 4) {
        int g0 = lst[e], g1 = lst[e + 1], g2 = lst[e + 2], g3 = lst[e + 3];
        float w0 = expf(pre_max[g0] - m), w1 = expf(pre_max[g1] - m);
        float w2 = expf(pre_max[g2] - m), w3 = expf(pre_max[g3] - m);
        a0 += w0 * x[(long)qrow(g0) * DD + t];
        a1 += w1 * x[(long)qrow(g1) * DD + t];
        a2 += w2 * x[(long)qrow(g2) * DD + t];
        a3 += w3 * x[(long)qrow(g3) * DD + t];
    }
    for (; e < cnt; e++) {
        int g0 = lst[e];
        a0 += expf(pre_max[g0] - m) * x[(long)qrow(g0) * DD + t];
    }
    float ap = ((a0 + a1) + (a2 + a3)) / Z;
    float n2 = blk_reduce_sum(ap * ap, red);
    apn[c * DD + t] = ap / sqrtf(n2);
}

// ---------- K4: bf16 MFMA coarse cosines, LDS-STAGED candidate tiles ----------
// (R4 verified: spill gone, simtopk off the top-5. Unchanged this round.)
#define COMPUTE_TILE_L(LBUF, TILE)                                                 \
    {                                                                              \
        f32x4 acc = {0.f, 0.f, 0.f, 0.f};                                          \
        _Pragma("unroll")                                                          \
        for (int kc = 0; kc < 8; kc++) {                                           \
            short8 cf = *(const short8*)((LBUF) + ((nn << 8) + (((kc * 4 + qd) ^ xm) << 3))); \
            acc = __builtin_amdgcn_mfma_f32_16x16x32_bf16(cf, qh[kc], acc, 0, 0, 0); \
        }                                                                          \
        _Pragma("unroll")                                                          \
        for (int r = 0; r < 4; ++r) {                                              \
            unsigned int u = __float_as_uint(acc[r]);                              \
            unsigned int key = u ^ (unsigned int)(((int)u >> 31) | 0x80000000);    \
            key = (key & 0xFFFFFC00u) | (unsigned int)((TILE) * 16 + 4 * qd + r);  \
            if (key > keys[QK - 1]) {                                              \
                unsigned int ck = key;                                             \
                _Pragma("unroll")                                                  \
                for (int p = 0; p < QK; ++p) {                                     \
                    bool sw = ck > keys[p];                                        \
                    unsigned int tmp = keys[p];                                    \
                    keys[p] = sw ? ck : keys[p];                                   \
                    ck = sw ? tmp : ck;                                            \
                }                                                                  \
            }                                                                      \
        }                                                                          \
    }

#define GLOAD(RA, RB, TL)                                                          \
    {                                                                              \
        const unsigned short* tb = xh + ((size_t)(col0 + (TL) * 16) << 8);         \
        RA = *(const uint4*)(tb + (G0 << 3));                                      \
        RB = *(const uint4*)(tb + (G1 << 3));                                      \
    }

#define DSWRITE(LBUF, RA, RB)                                                      \
    {                                                                              \
        *(uint4*)((LBUF) + (u0 << 3)) = RA;                                        \
        *(uint4*)((LBUF) + (u1 << 3)) = RB;                                        \
    }

__global__ __launch_bounds__(256, 4) void simtopk_kernel(const unsigned short* __restrict__ xh,
                                                         int* __restrict__ topi4) {
    __shared__ uint4 smem4[1024];   // 16 KB: 2x8KB tile double-buffer; aliased as dump
    unsigned short* T0 = (unsigned short*)smem4;
    unsigned short* T1 = (unsigned short*)smem4 + 4096;

    const int t = threadIdx.x;
    const int b = blockIdx.x;
    const int rb = b >> 3;          // 128 row-blocks of 64 rows
    const int ch = b & 7;           // column chunk
    const int row0 = rb * 64;
    const int col0 = ch * 1024;

    const int wv = t >> 6;
    const int lane = t & 63;
    const int qd = lane >> 4;
    const int nn = lane & 15;
    const int xm = nn & 7;

    // staging geometry: tile = 512 x 16B units; thread handles G0=t, G1=256+t
    const int G0 = t;
    const int G1 = 256 + t;
    const int r0r = G0 >> 5, c0u = G0 & 31;
    const int u0 = r0r * 32 + (c0u ^ (r0r & 7));
    const int r1r = G1 >> 5, c1u = G1 & 31;
    const int u1 = r1r * 32 + (c1u ^ (r1r & 7));

    // Query fragments (MFMA B operand): lane holds Q[n=nn][k=kc*32+qd*8 ..+7]
    const int arow = (row0 + wv * 16 + nn) * DD;
    short8 qh[8];
    #pragma unroll
    for (int kc = 0; kc < 8; kc++)
        qh[kc] = *(const short8*)(xh + arow + kc * 32 + qd * 8);

    unsigned int keys[QK];
    #pragma unroll
    for (int s = 0; s < QK; s++) keys[s] = 0u;   // below any real score's key

    uint4 RA, RB;
    GLOAD(RA, RB, 0)
    DSWRITE(T0, RA, RB)
    __syncthreads();                         // T0 ready

    #pragma unroll 1
    for (int t2 = 0; t2 < 32; ++t2) {
        GLOAD(RA, RB, 2 * t2 + 1)            // issue early (hides under compute)
        COMPUTE_TILE_L(T0, 2 * t2)
        __syncthreads();                     // all waves done reading T1 (prev iter)
        DSWRITE(T1, RA, RB)
        if (t2 < 31) GLOAD(RA, RB, 2 * t2 + 2)
        __syncthreads();                     // T1 ready
        COMPUTE_TILE_L(T1, 2 * t2 + 1)
        __syncthreads();                     // all waves done reading T0
        if (t2 < 31) { DSWRITE(T0, RA, RB) }
        __syncthreads();                     // T0 ready
    }

    // dump (aliases tile buffers; all tile reads are behind the final barrier).
    unsigned int* dw = (unsigned int*)smem4 + wv * (13 * 64);
    #pragma unroll
    for (int s = 0; s < QK; s++) dw[lane * 13 + s] = keys[s];
    if (lane < 16) {
        const int g = row0 + wv * 16 + lane;
        const int b0 = (lane +  0) * 13;
        const int b1 = (lane + 16) * 13;
        const int b2 = (lane + 32) * 13;
        const int b3 = (lane + 48) * 13;
        int p0 = 0, p1 = 0, p2 = 0, p3 = 0;
        for (int s = 0; s < QK; s++) {
            unsigned int v0 = (p0 < QK) ? dw[b0 + p0] : 0u;
            unsigned int v1 = (p1 < QK) ? dw[b1 + p1] : 0u;
            unsigned int v2 = (p2 < QK) ? dw[b2 + p2] : 0u;
            unsigned int v3 = (p3 < QK) ? dw[b3 + p3] : 0u;
            unsigned int bv = v0; int bw = 0;
            if (v1 > bv) { bv = v1; bw = 1; }
            if (v2 > bv) { bv = v2; bw = 2; }
            if (v3 > bv) { bv = v3; bw = 3; }
            topi4[g * CAND + ch * QK + s] = col0 + (int)(bv & 1023u);
            if (bw == 0) p0++; else if (bw == 1) p1++; else if (bw == 2) p2++; else p3++;
        }
    }
}

// ---------- K5: exact fp32 rescoring, coalesced + 8-deep ILP ----------
// R4 lesson: VGPR_Count=16 (default launch_bounds min-registered) = ONE row in
// flight -> 24 serial ~400cyc gathers/wave. Fix: (256,4) reg budget + wave w
// owns candidates [24w,24w+24) in 3 rounds of 8-in-flight gathers; shuffle
// reduces interleaved across the 8 chains. ~75 VGPR, far from R3's spill.
__global__ __launch_bounds__(256, 4) void rescore_kernel(const float* __restrict__ x,
                                                         const float* __restrict__ qInv,
                                                         const int* __restrict__ topi4,
                                                         float* __restrict__ topv,
                                                         int* __restrict__ topi) {
    __shared__ float sc[CAND];
    __shared__ int   si[CAND];
    const int g = blockIdx.x;
    const int t = threadIdx.x;
    const int lane = t & 63;
    const int w = t >> 6;            // wave id: candidates [24w, 24w+24)
    const float4 a4 = *(const float4*)(x + (long)qrow(g) * DD + lane * 4);
    const float qg = qInv[g];
    #pragma unroll 1
    for (int r = 0; r < 3; ++r) {
        const int c0 = w * 24 + r * 8;
        int jj[8];
        #pragma unroll
        for (int u = 0; u < 8; u++) {
            int j = topi4[g * CAND + c0 + u];
            jj[u] = ((unsigned)j < NQ) ? j : 0;
        }
        float4 b[8];
        #pragma unroll
        for (int u = 0; u < 8; u++)
            b[u] = *(const float4*)(x + (long)qrow(jj[u]) * DD + lane * 4);
        float qj[8];
        #pragma unroll
        for (int u = 0; u < 8; u++) qj[u] = qInv[jj[u]];
        float p[8];
        #pragma unroll
        for (int u = 0; u < 8; u++)
            p[u] = a4.x * b[u].x + a4.y * b[u].y + a4.z * b[u].z + a4.w * b[u].w;
        #pragma unroll
        for (int off = 32; off > 0; off >>= 1) {
            #pragma unroll
            for (int u = 0; u < 8; u++) p[u] += __shfl_xor(p[u], off);
        }
        if (lane == 0) {
            #pragma unroll
            for (int u = 0; u < 8; u++) { sc[c0 + u] = p[u] * qj[u] * qg; si[c0 + u] = jj[u]; }
        }
    }
    __syncthreads();
    if (t == 0) {
        float Lv[KNB]; int Li[KNB];
        for (int s = 0; s < KNB; s++) { Lv[s] = -INFINITY; Li[s] = 0x7fffffff; }
        #pragma unroll 4
        for (int q = 0; q < CAND; q++) {
            float v = sc[q]; int idx = si[q];
            if (v > Lv[KNB - 1] || (v == Lv[KNB - 1] && idx < Li[KNB - 1])) {
                int p = KNB - 1;
                while (p > 0 && (Lv[p - 1] < v || (Lv[p - 1] == v && Li[p - 1] > idx))) {
                    Lv[p] = Lv[p - 1]; Li[p] = Li[p - 1]; p--;
                }
                Lv[p] = v; Li[p] = idx;
            }
        }
        for (int s = 0; s < KNB; s++) {
            topv[g * KNB + s] = Lv[s];
            topi[g * KNB + s] = Li[s];
        }
    }
}

// ---------- K6: mutual-kNN softmax, adapted query, final cos sims ----------
__global__ __launch_bounds__(256) void final_kernel(const float* __restrict__ x,
                                                    const float* __restrict__ apn,
                                                    const float* __restrict__ topv,
                                                    const int* __restrict__ topi,
                                                    const float* __restrict__ tao_raw,
                                                    float* out) {
    __shared__ float tv[KNB]; __shared__ int ti[KNB]; __shared__ float w[KNB];
    __shared__ float aq[256]; __shared__ float red[256];
    int i = blockIdx.x, t = threadIdx.x;
    if (t < KNB) {
        tv[t] = topv[i * KNB + t];
        int j = topi[i * KNB + t];
        ti[t] = ((unsigned)j < NQ) ? j : 0;
    }
    __syncthreads();
    if (t < KNB) {
        int j = ti[t];
        bool mut = false;
        for (int s = 0; s < KNB; s++) mut = mut || (topi[j * KNB + s] == i);
        w[t] = mut ? tv[t] : -INFINITY;
    }
    __syncthreads();
    if (t == 0) {
        float m = -INFINITY;
        for (int s = 0; s < KNB; s++) m = fmaxf(m, w[s]);
        float e[KNB]; float Z = 0.f;
        for (int s = 0; s < KNB; s++) { e[s] = expf(w[s] - m); Z += e[s]; }
        for (int s = 0; s < KNB; s++) w[s] = e[s] / Z;
    }
    __syncthreads();
    float a = 0.f;
    for (int s = 0; s < KNB; s++) {
        float ws = w[s];
        if (ws != 0.f) a += ws * x[(long)qrow(ti[s]) * DD + t];
    }
    aq[t] = a;
    float n2 = blk_reduce_sum(a * a, red);
    float inv = 1.f / sqrtf(n2);
    int c = t >> 2, tl = t & 3;
    float sdot = 0.f;
    for (int u = 0; u < 64; u++) sdot += aq[tl * 64 + u] * apn[c * DD + tl * 64 + u];
    red[t] = sdot; __syncthreads();
    if (tl == 0) {
        float sv = red[t] + red[t + 1] + red[t + 2] + red[t + 3];
        out[i * NCLS + c] = tao_raw[0] * sv * inv;
    }
}

extern "C" void kernel_launch(void* const* d_in, const int* in_sizes, int n_in,
                              void* d_out, int out_size, void* d_ws, size_t ws_size,
                              hipStream_t stream) {
    (void)in_sizes; (void)n_in; (void)out_size;
    const float* x   = (const float*)d_in[0];
    const float* tao = (const float*)d_in[1];
    float* out = (float*)d_out;

    char* ws = (char*)d_ws;
    size_t off = 0;
    auto carve = [&](size_t bytes) {
        void* p = ws + off;
        off = (off + bytes + 255) & ~(size_t)255;
        return p;
    };
    float*          proto   = (float*)carve(NCLS * DD * 4);
    float*          pn      = (float*)carve(NCLS * DD * 4);
    float*          selfs   = (float*)carve(NCLS * 4);
    float*          qInv    = (float*)carve(NQ * 4);
    float*          pre_max = (float*)carve(NQ * 4);
    int*            pre_lab = (int*)carve(NQ * 4);
    float*          apn     = (float*)carve(NCLS * DD * 4);
    unsigned short* xh      = (unsigned short*)carve((size_t)NQ * DD * 2);
    int*            topi4   = (int*)carve((size_t)NQ * CAND * 4);
    float*          topv    = (float*)carve((size_t)NQ * KNB * 4);
    int*            topi    = (int*)carve((size_t)NQ * KNB * 4);
    if (off > ws_size) return;

    split_kernel<<<NQ, 256, 0, stream>>>(x, xh, qInv);
    proto_kernel<<<NCLS, 256, 0, stream>>>(x, proto, pn, selfs);
    presim_kernel<<<NQ, 256, 0, stream>>>(x, qInv, pn, pre_max, pre_lab);
    adapt_proto_kernel<<<NCLS, 256, 0, stream>>>(x, proto, selfs, pre_max, pre_lab, apn);
    simtopk_kernel<<<NQ / 64 * NCH, 256, 0, stream>>>(xh, topi4);
    rescore_kernel<<<NQ, 256, 0, stream>>>(x, qInv, topi4, topv, topi);
    final_kernel<<<NQ, 256, 0, stream>>>(x, apn, topv, topi, tao, out);
}

// Round 6
// 408.084 us; speedup vs baseline: 1.6964x; 1.0997x over previous
//
#include <hip/hip_runtime.h>
#include <math.h>

#define NCLS 64
#define KS 5
#define DD 256
#define NQ 8192   // NCLS*128
#define KNB 10
#define QK 12     // per-chunk candidate list depth (need >=10 for exact containment)
#define NCH 8     // column chunks per row (1024 cols each)
#define CAND 96   // NCH * QK

typedef __attribute__((ext_vector_type(8))) short short8;   // 8 bf16 bit-patterns (4 VGPRs)
typedef __attribute__((ext_vector_type(4))) float f32x4;    // MFMA C/D frag

// row index in x (fp32 row units) of query g
__device__ __forceinline__ int qrow(int g) { return (g >> 7) * 133 + KS + (g & 127); }

__device__ __forceinline__ unsigned short bf16_rne(float f) {
    unsigned int u = __float_as_uint(f);
    u += 0x7fffu + ((u >> 16) & 1u);
    return (unsigned short)(u >> 16);
}

__device__ __forceinline__ float blk_reduce_sum(float v, float* red) {
    int t = threadIdx.x;
    red[t] = v; __syncthreads();
    for (int off = 128; off > 0; off >>= 1) {
        if (t < off) red[t] += red[t + off];
        __syncthreads();
    }
    float r = red[0];
    __syncthreads();
    return r;
}

__device__ __forceinline__ float blk_reduce_max(float v, float* red) {
    int t = threadIdx.x;
    red[t] = v; __syncthreads();
    for (int off = 128; off > 0; off >>= 1) {
        if (t < off) red[t] = fmaxf(red[t], red[t + off]);
        __syncthreads();
    }
    float r = red[0];
    __syncthreads();
    return r;
}

// ---------- K0: NORMALIZED bf16 cast of query rows + qInv ----------
__global__ __launch_bounds__(256) void split_kernel(const float* __restrict__ x,
                                                    unsigned short* __restrict__ xh,
                                                    float* __restrict__ qInv) {
    __shared__ float red[256];
    int g = blockIdx.x, t = threadIdx.x;
    float v = x[(long)qrow(g) * DD + t];
    float n2 = blk_reduce_sum(v * v, red);
    float inv = 1.f / sqrtf(n2);
    xh[g * DD + t] = bf16_rne(v * inv);
    if (t == 0) qInv[g] = inv;
}

// ---------- K1: proto, pn, self_sim ----------
__global__ __launch_bounds__(256) void proto_kernel(const float* __restrict__ x,
                                                    float* proto, float* pn, float* selfs) {
    __shared__ float red[256];
    int c = blockIdx.x, t = threadIdx.x;
    float s = 0.f;
    for (int j = 0; j < KS; j++) s += x[(long)(c * 133 + j) * DD + t];
    float p = s / 5.0f;
    proto[c * DD + t] = p;
    float n2 = blk_reduce_sum(p * p, red);
    float pv = p / sqrtf(n2);
    pn[c * DD + t] = pv;
    float ss = blk_reduce_sum(pv * pv, red);
    if (t == 0) selfs[c] = ss;
}

// ---------- K2: pre_sim argmax per query (float4 loads, same fma order) ----------
__global__ __launch_bounds__(256) void presim_kernel(const float* __restrict__ x,
                                                     const float* __restrict__ qInv,
                                                     const float* __restrict__ pn,
                                                     float* pre_max, int* pre_label) {
    __shared__ __align__(16) float qs[256];
    __shared__ float part[256];
    __shared__ float sims[64];
    int g = blockIdx.x, t = threadIdx.x;
    qs[t] = x[(long)qrow(g) * DD + t];
    __syncthreads();
    int c = t >> 2, tl = t & 3;
    float s = 0.f;
    const float4* qp = (const float4*)(qs + tl * 64);
    const float4* pp = (const float4*)(pn + c * DD + tl * 64);
    #pragma unroll
    for (int u4 = 0; u4 < 16; u4++) {
        float4 a = qp[u4], b = pp[u4];
        s += a.x * b.x; s += a.y * b.y; s += a.z * b.z; s += a.w * b.w;
    }
    part[t] = s; __syncthreads();
    if (tl == 0) sims[c] = part[t] + part[t + 1] + part[t + 2] + part[t + 3];
    __syncthreads();
    if (t == 0) {
        float best = sims[0]; int bi = 0;
        for (int c2 = 1; c2 < 64; c2++)
            if (sims[c2] > best) { best = sims[c2]; bi = c2; }
        pre_max[g] = best * qInv[g];
        pre_label[g] = bi;
    }
}

// ---------- K3: adapted prototypes — LDS-compacted member list ----------
__global__ __launch_bounds__(256) void adapt_proto_kernel(const float* __restrict__ x,
                                                          const float* __restrict__ proto,
                                                          const float* __restrict__ selfs,
                                                          const float* __restrict__ pre_max,
                                                          const int* __restrict__ pre_label,
                                                          float* apn) {
    __shared__ int lst[NQ];
    __shared__ float red[256];
    __shared__ int cnt_s;
    int c = blockIdx.x, t = threadIdx.x;
    if (t == 0) cnt_s = 0;
    __syncthreads();
    float lm = -INFINITY;
    for (int g = t; g < NQ; g += 256) {
        if (pre_label[g] == c) {
            int p = atomicAdd(&cnt_s, 1);
            lst[p] = g;
            lm = fmaxf(lm, pre_max[g]);
        }
    }
    float m = fmaxf(blk_reduce_max(lm, red), selfs[c]);   // barrier publishes lst/cnt_s
    int cnt = cnt_s;
    float ls = 0.f;
    for (int e = t; e < cnt; e += 256) ls += expf(pre_max[lst[e]] - m);
    float es = expf(selfs[c] - m);
    float Z = blk_reduce_sum(ls, red) + es;
    float a0 = es * proto[c * DD + t], a1 = 0.f, a2 = 0.f, a3 = 0.f;
    int e = 0;
    for (; e + 3 < cnt; e += 4) {
        int g0 = lst[e], g1 = lst[e + 1], g2 = lst[e + 2], g3 = lst[e + 3];
        float w0 = expf(pre_max[g0] - m), w1 = expf(pre_max[g1] - m);
        float w2 = expf(pre_max[g2] - m), w3 = expf(pre_max[g3] - m);
        a0 += w0 * x[(long)qrow(g0) * DD + t];
        a1 += w1 * x[(long)qrow(g1) * DD + t];
        a2 += w2 * x[(long)qrow(g2) * DD + t];
        a3 += w3 * x[(long)qrow(g3) * DD + t];
    }
    for (; e < cnt; e++) {
        int g0 = lst[e];
        a0 += expf(pre_max[g0] - m) * x[(long)qrow(g0) * DD + t];
    }
    float ap = ((a0 + a1) + (a2 + a3)) / Z;
    float n2 = blk_reduce_sum(ap * ap, red);
    apn[c * DD + t] = ap / sqrtf(n2);
}

// ---------- K4: bf16 MFMA coarse cosines, LDS-STAGED candidate tiles ----------
// (R4 verified. Unchanged.)
#define COMPUTE_TILE_L(LBUF, TILE)                                                 \
    {                                                                              \
        f32x4 acc = {0.f, 0.f, 0.f, 0.f};                                          \
        _Pragma("unroll")                                                          \
        for (int kc = 0; kc < 8; kc++) {                                           \
            short8 cf = *(const short8*)((LBUF) + ((nn << 8) + (((kc * 4 + qd) ^ xm) << 3))); \
            acc = __builtin_amdgcn_mfma_f32_16x16x32_bf16(cf, qh[kc], acc, 0, 0, 0); \
        }                                                                          \
        _Pragma("unroll")                                                          \
        for (int r = 0; r < 4; ++r) {                                              \
            unsigned int u = __float_as_uint(acc[r]);                              \
            unsigned int key = u ^ (unsigned int)(((int)u >> 31) | 0x80000000);    \
            key = (key & 0xFFFFFC00u) | (unsigned int)((TILE) * 16 + 4 * qd + r);  \
            if (key > keys[QK - 1]) {                                              \
                unsigned int ck = key;                                             \
                _Pragma("unroll")                                                  \
                for (int p = 0; p < QK; ++p) {                                     \
                    bool sw = ck > keys[p];                                        \
                    unsigned int tmp = keys[p];                                    \
                    keys[p] = sw ? ck : keys[p];                                   \
                    ck = sw ? tmp : ck;                                            \
                }                                                                  \
            }                                                                      \
        }                                                                          \
    }

#define GLOAD(RA, RB, TL)                                                          \
    {                                                                              \
        const unsigned short* tb = xh + ((size_t)(col0 + (TL) * 16) << 8);         \
        RA = *(const uint4*)(tb + (G0 << 3));                                      \
        RB = *(const uint4*)(tb + (G1 << 3));                                      \
    }

#define DSWRITE(LBUF, RA, RB)                                                      \
    {                                                                              \
        *(uint4*)((LBUF) + (u0 << 3)) = RA;                                        \
        *(uint4*)((LBUF) + (u1 << 3)) = RB;                                        \
    }

__global__ __launch_bounds__(256, 4) void simtopk_kernel(const unsigned short* __restrict__ xh,
                                                         int* __restrict__ topi4) {
    __shared__ uint4 smem4[1024];   // 16 KB: 2x8KB tile double-buffer; aliased as dump
    unsigned short* T0 = (unsigned short*)smem4;
    unsigned short* T1 = (unsigned short*)smem4 + 4096;

    const int t = threadIdx.x;
    const int b = blockIdx.x;
    const int rb = b >> 3;          // 128 row-blocks of 64 rows
    const int ch = b & 7;           // column chunk
    const int row0 = rb * 64;
    const int col0 = ch * 1024;

    const int wv = t >> 6;
    const int lane = t & 63;
    const int qd = lane >> 4;
    const int nn = lane & 15;
    const int xm = nn & 7;

    const int G0 = t;
    const int G1 = 256 + t;
    const int r0r = G0 >> 5, c0u = G0 & 31;
    const int u0 = r0r * 32 + (c0u ^ (r0r & 7));
    const int r1r = G1 >> 5, c1u = G1 & 31;
    const int u1 = r1r * 32 + (c1u ^ (r1r & 7));

    const int arow = (row0 + wv * 16 + nn) * DD;
    short8 qh[8];
    #pragma unroll
    for (int kc = 0; kc < 8; kc++)
        qh[kc] = *(const short8*)(xh + arow + kc * 32 + qd * 8);

    unsigned int keys[QK];
    #pragma unroll
    for (int s = 0; s < QK; s++) keys[s] = 0u;

    uint4 RA, RB;
    GLOAD(RA, RB, 0)
    DSWRITE(T0, RA, RB)
    __syncthreads();                         // T0 ready

    #pragma unroll 1
    for (int t2 = 0; t2 < 32; ++t2) {
        GLOAD(RA, RB, 2 * t2 + 1)
        COMPUTE_TILE_L(T0, 2 * t2)
        __syncthreads();
        DSWRITE(T1, RA, RB)
        if (t2 < 31) GLOAD(RA, RB, 2 * t2 + 2)
        __syncthreads();
        COMPUTE_TILE_L(T1, 2 * t2 + 1)
        __syncthreads();
        if (t2 < 31) { DSWRITE(T0, RA, RB) }
        __syncthreads();
    }

    unsigned int* dw = (unsigned int*)smem4 + wv * (13 * 64);
    #pragma unroll
    for (int s = 0; s < QK; s++) dw[lane * 13 + s] = keys[s];
    if (lane < 16) {
        const int g = row0 + wv * 16 + lane;
        const int b0 = (lane +  0) * 13;
        const int b1 = (lane + 16) * 13;
        const int b2 = (lane + 32) * 13;
        const int b3 = (lane + 48) * 13;
        int p0 = 0, p1 = 0, p2 = 0, p3 = 0;
        for (int s = 0; s < QK; s++) {
            unsigned int v0 = (p0 < QK) ? dw[b0 + p0] : 0u;
            unsigned int v1 = (p1 < QK) ? dw[b1 + p1] : 0u;
            unsigned int v2 = (p2 < QK) ? dw[b2 + p2] : 0u;
            unsigned int v3 = (p3 < QK) ? dw[b3 + p3] : 0u;
            unsigned int bv = v0; int bw = 0;
            if (v1 > bv) { bv = v1; bw = 1; }
            if (v2 > bv) { bv = v2; bw = 2; }
            if (v3 > bv) { bv = v3; bw = 3; }
            topi4[g * CAND + ch * QK + s] = col0 + (int)(bv & 1023u);
            if (bw == 0) p0++; else if (bw == 1) p1++; else if (bw == 2) p2++; else p3++;
        }
    }
}

// ---------- K5a: exact fp32 rescoring — wave-per-24-candidates, max TLP ----------
// R5 lesson: 4-wave block + barriers + serial t==0 tail capped occupancy at 46%
// and the compiler kept ILP shallow (VGPR=40). Fix: 64-thr blocks (grid NQ*4),
// no barriers/tail; VGPR<=64 -> 8 waves/SIMD = 32 waves/CU. 32 waves x >=2
// outstanding 1KB row-loads/CU >> latency-BW product -> L2-BW-bound (~25-40us
// floor). Indices readfirstlane'd to SGPR (saddr loads, scalar qInv).
__global__ __launch_bounds__(64, 8) void rescore_kernel(const float* __restrict__ x,
                                                        const float* __restrict__ qInv,
                                                        const int* __restrict__ topi4,
                                                        float* __restrict__ scoreb) {
    const int wid = blockIdx.x;
    const int g = wid >> 2;
    const int w = wid & 3;            // wave's candidate group [24w, 24w+24)
    const int lane = threadIdx.x;
    const float4 a4 = *(const float4*)(x + (long)qrow(g) * DD + lane * 4);
    const float qg = qInv[g];
    const int cb = g * CAND + w * 24;
    #pragma unroll 1
    for (int r = 0; r < 3; ++r) {
        const int c0 = cb + r * 8;
        int jj[8];
        #pragma unroll
        for (int u = 0; u < 8; u++) {
            int j = topi4[c0 + u];
            jj[u] = __builtin_amdgcn_readfirstlane(((unsigned)j < NQ) ? j : 0);
        }
        float4 b[8];
        #pragma unroll
        for (int u = 0; u < 8; u++)
            b[u] = *(const float4*)(x + (long)qrow(jj[u]) * DD + lane * 4);
        float p[8];
        #pragma unroll
        for (int u = 0; u < 8; u++)
            p[u] = a4.x * b[u].x + a4.y * b[u].y + a4.z * b[u].z + a4.w * b[u].w;
        #pragma unroll
        for (int off = 32; off > 0; off >>= 1) {
            #pragma unroll
            for (int u = 0; u < 8; u++) p[u] += __shfl_xor(p[u], off);
        }
        if (lane == 0) {
            #pragma unroll
            for (int u = 0; u < 8; u++) scoreb[c0 + u] = p[u] * qInv[jj[u]] * qg;
        }
    }
}

// ---------- K5b: wave-parallel top-10 of the 96 rescored candidates ----------
// Replaces the per-block serial 96-step insertion tail. 10 rounds of 64-lane
// shuffle-argmax with (value desc, idx asc) tie rule — same ordering as before.
__global__ __launch_bounds__(64) void topk_kernel(const float* __restrict__ scoreb,
                                                  const int* __restrict__ topi4,
                                                  float* __restrict__ topv,
                                                  int* __restrict__ topi) {
    const int g = blockIdx.x;
    const int lane = threadIdx.x;
    float v0 = scoreb[g * CAND + lane];
    int j0 = topi4[g * CAND + lane];
    int i0 = ((unsigned)j0 < NQ) ? j0 : 0;
    float v1 = -INFINITY; int i1 = 0x7fffffff;
    if (lane < CAND - 64) {
        v1 = scoreb[g * CAND + 64 + lane];
        int j1 = topi4[g * CAND + 64 + lane];
        i1 = ((unsigned)j1 < NQ) ? j1 : 0;
    }
    #pragma unroll 1
    for (int s = 0; s < KNB; ++s) {
        bool sel1 = (v1 > v0) || (v1 == v0 && i1 < i0);
        float bv = sel1 ? v1 : v0;
        int   bi = sel1 ? i1 : i0;
        #pragma unroll
        for (int off = 32; off > 0; off >>= 1) {
            float ov = __shfl_xor(bv, off);
            int   oi = __shfl_xor(bi, off);
            bool take = (ov > bv) || (ov == bv && oi < bi);
            bv = take ? ov : bv;
            bi = take ? oi : bi;
        }
        if (lane == 0) { topv[g * KNB + s] = bv; topi[g * KNB + s] = bi; }
        if (i0 == bi) v0 = -INFINITY;
        if (i1 == bi) v1 = -INFINITY;
    }
}

// ---------- K6: mutual-kNN softmax, adapted query, final cos sims ----------
__global__ __launch_bounds__(256) void final_kernel(const float* __restrict__ x,
                                                    const float* __restrict__ apn,
                                                    const float* __restrict__ topv,
                                                    const int* __restrict__ topi,
                                                    const float* __restrict__ tao_raw,
                                                    float* out) {
    __shared__ float tv[KNB]; __shared__ int ti[KNB]; __shared__ float w[KNB];
    __shared__ __align__(16) float aq[256]; __shared__ float red[256];
    int i = blockIdx.x, t = threadIdx.x;
    if (t < KNB) {
        tv[t] = topv[i * KNB + t];
        int j = topi[i * KNB + t];
        ti[t] = ((unsigned)j < NQ) ? j : 0;
    }
    __syncthreads();
    if (t < KNB) {
        int j = ti[t];
        bool mut = false;
        for (int s = 0; s < KNB; s++) mut = mut || (topi[j * KNB + s] == i);
        w[t] = mut ? tv[t] : -INFINITY;
    }
    __syncthreads();
    if (t == 0) {
        float m = -INFINITY;
        for (int s = 0; s < KNB; s++) m = fmaxf(m, w[s]);
        float e[KNB]; float Z = 0.f;
        for (int s = 0; s < KNB; s++) { e[s] = expf(w[s] - m); Z += e[s]; }
        for (int s = 0; s < KNB; s++) w[s] = e[s] / Z;
    }
    __syncthreads();
    float a = 0.f;
    for (int s = 0; s < KNB; s++) {
        float ws = w[s];
        if (ws != 0.f) a += ws * x[(long)qrow(ti[s]) * DD + t];
    }
    aq[t] = a;
    float n2 = blk_reduce_sum(a * a, red);
    float inv = 1.f / sqrtf(n2);
    int c = t >> 2, tl = t & 3;
    float sdot = 0.f;
    const float4* ap4 = (const float4*)(apn + c * DD + tl * 64);
    const float4* aq4 = (const float4*)(aq + tl * 64);
    #pragma unroll
    for (int u4 = 0; u4 < 16; u4++) {
        float4 av = aq4[u4], pv = ap4[u4];
        sdot += av.x * pv.x; sdot += av.y * pv.y; sdot += av.z * pv.z; sdot += av.w * pv.w;
    }
    red[t] = sdot; __syncthreads();
    if (tl == 0) {
        float sv = red[t] + red[t + 1] + red[t + 2] + red[t + 3];
        out[i * NCLS + c] = tao_raw[0] * sv * inv;
    }
}

extern "C" void kernel_launch(void* const* d_in, const int* in_sizes, int n_in,
                              void* d_out, int out_size, void* d_ws, size_t ws_size,
                              hipStream_t stream) {
    (void)in_sizes; (void)n_in; (void)out_size;
    const float* x   = (const float*)d_in[0];
    const float* tao = (const float*)d_in[1];
    float* out = (float*)d_out;

    char* ws = (char*)d_ws;
    size_t off = 0;
    auto carve = [&](size_t bytes) {
        void* p = ws + off;
        off = (off + bytes + 255) & ~(size_t)255;
        return p;
    };
    float*          proto   = (float*)carve(NCLS * DD * 4);
    float*          pn      = (float*)carve(NCLS * DD * 4);
    float*          selfs   = (float*)carve(NCLS * 4);
    float*          qInv    = (float*)carve(NQ * 4);
    float*          pre_max = (float*)carve(NQ * 4);
    int*            pre_lab = (int*)carve(NQ * 4);
    float*          apn     = (float*)carve(NCLS * DD * 4);
    unsigned short* xh      = (unsigned short*)carve((size_t)NQ * DD * 2);
    int*            topi4   = (int*)carve((size_t)NQ * CAND * 4);
    float*          topv    = (float*)carve((size_t)NQ * KNB * 4);
    int*            topi    = (int*)carve((size_t)NQ * KNB * 4);
    float*          scoreb  = (float*)carve((size_t)NQ * CAND * 4);
    if (off > ws_size) return;

    split_kernel<<<NQ, 256, 0, stream>>>(x, xh, qInv);
    proto_kernel<<<NCLS, 256, 0, stream>>>(x, proto, pn, selfs);
    presim_kernel<<<NQ, 256, 0, stream>>>(x, qInv, pn, pre_max, pre_lab);
    adapt_proto_kernel<<<NCLS, 256, 0, stream>>>(x, proto, selfs, pre_max, pre_lab, apn);
    simtopk_kernel<<<NQ / 64 * NCH, 256, 0, stream>>>(xh, topi4);
    rescore_kernel<<<NQ * 4, 64, 0, stream>>>(x, qInv, topi4, scoreb);
    topk_kernel<<<NQ, 64, 0, stream>>>(scoreb, topi4, topv, topi);
    final_kernel<<<NQ, 256, 0, stream>>>(x, apn, topv, topi, tao, out);
}